// Round 1
// baseline (125.496 us; speedup 1.0000x reference)
//
#include <hip/hip_runtime.h>
#include <math.h>

// Problem constants
#define NV 32      // num_vari (groups)
#define NB 4096    // batch
#define NK 256     // 2*dim_per_vari (contraction)
#define NO 256     // dim_to (output features)

// Tiling
#define BM 64      // batch rows per block
#define BK 32      // k per LDS tile
#define NKT (NK / BK)  // 8 k-steps
#define LSTR 40    // LDS row stride in bf16 elems (32 + 8 pad -> 80B, breaks 2^k bank pattern)

typedef __bf16 bf16x8 __attribute__((ext_vector_type(8)));
typedef float  f32x4  __attribute__((ext_vector_type(4)));

__device__ __forceinline__ f32x4 mfma16(bf16x8 a, bf16x8 b, f32x4 c) {
    return __builtin_amdgcn_mfma_f32_16x16x32_bf16(a, b, c, 0, 0, 0);
}

__device__ __forceinline__ float softplus_f(float z) {
    // numerically stable: max(z,0) + log1p(exp(-|z|)); |z| can reach ~50 (bias*256)
    return fmaxf(z, 0.0f) + log1pf(__expf(-fabsf(z)));
}

__global__ __launch_bounds__(256, 2)
void mv_dense_kernel(const float* __restrict__ x, const float* __restrict__ w,
                     const float* __restrict__ bias, float* __restrict__ out) {
    // A tile: x rows (bf16), B tile: W^T (bf16, [o][k]) -- double buffered
    __shared__ __bf16 As[2][BM][LSTR];   // 10,240 B
    __shared__ __bf16 Bs[2][NO][LSTR];   // 40,960 B  (total 50 KB)

    const int t    = threadIdx.x;
    const int bid  = blockIdx.x;
    const int v    = bid >> 6;    // 64 m-blocks per group
    const int mb   = bid & 63;

    const float* xg = x    + ((size_t)v * NB + (size_t)mb * BM) * NK;
    const float* wg = w    + (size_t)v * NK * NO;
    const float* bg = bias + (size_t)v * NO;
    float*       og = out  + ((size_t)v * NB + (size_t)mb * BM) * NO;

    const int wav  = t >> 6;      // wave 0..3 -> o-columns [wav*64, wav*64+64)
    const int lane = t & 63;
    const int lr   = lane & 15;   // fragment row/col within 16
    const int lg   = lane >> 4;   // k-group (8 contiguous k each)

    // staging assignments
    const int ar  = t >> 2;         // A: row 0..63
    const int ak  = (t & 3) * 8;    // A: k-offset {0,8,16,24}
    const int bo  = (t & 63) * 4;   // B: o base (4 cols per thread)
    const int bk  = (t >> 6) * 8;   // B: k base per wave {0,8,16,24}
    const int rot = lane & 3;       // write-order rotation (bank-conflict fix)

    // bias, pre-scaled by TWO_D=256, laid out to match C-fragment (4 consecutive o per lane)
    f32x4 bb[4];
#pragma unroll
    for (int j = 0; j < 4; ++j) {
        f32x4 bv = *(const f32x4*)(bg + wav * 64 + j * 16 + lg * 4);
#pragma unroll
        for (int r = 0; r < 4; ++r) bb[j][r] = 256.0f * bv[r];
    }

    f32x4 acc[4][4];
#pragma unroll
    for (int i = 0; i < 4; ++i)
#pragma unroll
        for (int j = 0; j < 4; ++j) {
            f32x4 z4 = {0.f, 0.f, 0.f, 0.f};
            acc[i][j] = z4;
        }

    // stage k-tile kt into LDS buffer buf (global fp32 -> bf16, W transposed)
    auto stage = [&](int kt, int buf) {
        const int k0 = kt * BK;
        // A: 8 contiguous k per thread (2x float4), one ds_write_b128
        f32x4 a0 = *(const f32x4*)(xg + (size_t)ar * NK + k0 + ak);
        f32x4 a1 = *(const f32x4*)(xg + (size_t)ar * NK + k0 + ak + 4);
        // B: 8 k-rows x 4 o-cols per thread, coalesced float4 row reads
        f32x4 wr[8];
#pragma unroll
        for (int j = 0; j < 8; ++j)
            wr[j] = *(const f32x4*)(wg + (size_t)(k0 + bk + j) * NO + bo);

        bf16x8 av;
#pragma unroll
        for (int e = 0; e < 4; ++e) { av[e] = (__bf16)a0[e]; av[e + 4] = (__bf16)a1[e]; }
        *(bf16x8*)&As[buf][ar][ak] = av;

        // transpose-write: column c of the float4s -> Bs[o=bo+c][k=bk..bk+7]
        // rotated write order so per-instruction rows are 4l+(l&3+cc)&3 -> spread banks
#pragma unroll
        for (int cc = 0; cc < 4; ++cc) {
            const int c = (cc + rot) & 3;
            bf16x8 bv;
#pragma unroll
            for (int j = 0; j < 8; ++j) bv[j] = (__bf16)wr[j][c];
            *(bf16x8*)&Bs[buf][bo + c][bk] = bv;
        }
    };

    stage(0, 0);
    __syncthreads();

#pragma unroll
    for (int kt = 0; kt < NKT; ++kt) {
        const int cur = kt & 1;
        if (kt + 1 < NKT) stage(kt + 1, cur ^ 1);  // issue next-tile loads early (T14-ish)

        // fragments: 8 contiguous k at k = 8*(lane>>4)  [verified gfx950 layout]
        bf16x8 afr[4];
#pragma unroll
        for (int i = 0; i < 4; ++i)
            afr[i] = *(const bf16x8*)&As[cur][i * 16 + lr][lg * 8];
#pragma unroll
        for (int j = 0; j < 4; ++j) {
            bf16x8 bfr = *(const bf16x8*)&Bs[cur][wav * 64 + j * 16 + lr][lg * 8];
#pragma unroll
            for (int i = 0; i < 4; ++i)
                // operand swap: A:=W^T frag, B:=x frag -> D[o][b]; lane then holds
                // 4 CONSECUTIVE o at one batch row -> float4 stores
                acc[i][j] = mfma16(bfr, afr[i], acc[i][j]);
        }
        __syncthreads();
    }

    // epilogue: C/D layout (16x16x32): col(=batch row)=lane&15, row(=o)=4*(lane>>4)+reg
#pragma unroll
    for (int i = 0; i < 4; ++i) {
        const size_t rowbase = (size_t)(i * 16 + lr) * NO;
#pragma unroll
        for (int j = 0; j < 4; ++j) {
            f32x4 res;
#pragma unroll
            for (int r = 0; r < 4; ++r)
                res[r] = softplus_f(acc[i][j][r] + bb[j][r]);
            *(f32x4*)(og + rowbase + wav * 64 + j * 16 + lg * 4) = res;
        }
    }
}

extern "C" void kernel_launch(void* const* d_in, const int* in_sizes, int n_in,
                              void* d_out, int out_size, void* d_ws, size_t ws_size,
                              hipStream_t stream) {
    const float* x  = (const float*)d_in[0];
    const float* w  = (const float*)d_in[1];
    const float* b  = (const float*)d_in[2];
    float* out      = (float*)d_out;

    // 32 groups x 64 m-blocks of 64 rows = 2048 blocks, 256 threads each
    hipLaunchKernelGGL(mv_dense_kernel, dim3(NV * (NB / BM)), dim3(256), 0, stream,
                       x, w, b, out);
}

// Round 2
// 90.205 us; speedup vs baseline: 1.3912x; 1.3912x over previous
//
#include <hip/hip_runtime.h>
#include <stdint.h>
#include <math.h>

// Problem constants
#define NV 32      // num_vari (groups)
#define NB 4096    // batch
#define NK 256     // 2*dim_per_vari (contraction)
#define NO 256     // dim_to (output features)

// Tiling
#define BM 64      // batch rows per block
#define BK 32      // k per LDS tile (64 B rows)
#define NKT (NK / BK)  // 8 k-steps

typedef __bf16 bf16x8 __attribute__((ext_vector_type(8)));
typedef float  f32x4  __attribute__((ext_vector_type(4)));

__device__ __forceinline__ f32x4 mfma16(bf16x8 a, bf16x8 b, f32x4 c) {
    return __builtin_amdgcn_mfma_f32_16x16x32_bf16(a, b, c, 0, 0, 0);
}

__device__ __forceinline__ float softplus_f(float z) {
    // |z| can reach ~55; for large z softplus(z)~z, error of fast log/exp ~1e-3 << 1.055 thr
    return fmaxf(z, 0.0f) + __logf(1.0f + __expf(-fabsf(z)));
}

__device__ __forceinline__ void gload_lds16(const void* g, void* l) {
    // async global->LDS, 16 B/lane; LDS dest is wave-uniform base + lane*16
    __builtin_amdgcn_global_load_lds((const __attribute__((address_space(1))) uint32_t*)g,
                                     (__attribute__((address_space(3))) uint32_t*)l,
                                     16, 0, 0);
}

// ---------------------------------------------------------------------------
// prep: W[v][k][o] fp32  ->  Wt[v][o][k] bf16  (transpose + convert, 4 MB)
// reads coalesced along o (lanes = consecutive o); writes scattered 16 B (ok, 4 MB)
__global__ __launch_bounds__(256)
void prep_wt_kernel(const float* __restrict__ w, __bf16* __restrict__ wt) {
    const int id = blockIdx.x * 256 + threadIdx.x;   // 32*256*32 = 262144
    const int o  = id & 255;
    const int kc = (id >> 8) & 31;    // 8-k chunk
    const int v  = id >> 13;
    const float* src = w + ((size_t)v * NK + (size_t)kc * 8) * NO + o;
    bf16x8 r;
#pragma unroll
    for (int j = 0; j < 8; ++j) r[j] = (__bf16)src[(size_t)j * NO];
    *(bf16x8*)(wt + ((size_t)v * NO + o) * NK + kc * 8) = r;
}

// ---------------------------------------------------------------------------
// main: out[v][b][o] = softplus( x[v][b][:] . Wt[v][o][:] + 256*bias[v][o] )
__global__ __launch_bounds__(256, 4)
void mv_dense_kernel(const float* __restrict__ x, const __bf16* __restrict__ wt,
                     const float* __restrict__ bias, float* __restrict__ out) {
    // swizzled layout: 16B chunk at logical slot sl of row r lives at phys slot
    // sl ^ ((r>>1)&3).  Fragment reads then hit 2 lanes/bank per 16-lane group.
    __shared__ __bf16 As[2][BM][BK];   // 8 KB
    __shared__ __bf16 Bs[2][NO][BK];   // 32 KB   (total 40 KB -> 4 blocks/CU)

    const int t    = threadIdx.x;
    const int bid  = blockIdx.x;
    const int v    = bid >> 6;    // 64 m-blocks per group
    const int mb   = bid & 63;

    const float*  xg = x    + ((size_t)v * NB + (size_t)mb * BM) * NK;
    const __bf16* wg = wt   + (size_t)v * NO * NK;
    const float*  bg = bias + (size_t)v * NO;
    float*        og = out  + ((size_t)v * NB + (size_t)mb * BM) * NO;

    const int wav  = t >> 6;      // wave -> o-columns [wav*64, wav*64+64)
    const int lane = t & 63;
    const int lr   = lane & 15;
    const int lg   = lane >> 4;

    // A staging: thread -> row ar, logical 8-elem chunk asl
    const int ar  = t >> 2;
    const int asl = t & 3;
    const int asp = asl ^ ((ar >> 1) & 3);          // phys slot (swizzled)

    // fragment read: phys slot of logical chunk lg for row ..+lr (row>>1&3 == lr>>1&3)
    const int sfrag = (lg ^ ((lr >> 1) & 3)) * 8;   // element offset in row

    // bias, pre-scaled by 256, laid out per C-fragment (4 consecutive o per lane)
    f32x4 bb[4];
#pragma unroll
    for (int j = 0; j < 4; ++j) {
        f32x4 bv = *(const f32x4*)(bg + wav * 64 + j * 16 + lg * 4);
#pragma unroll
        for (int r = 0; r < 4; ++r) bb[j][r] = 256.0f * bv[r];
    }

    f32x4 acc[4][4];
#pragma unroll
    for (int i = 0; i < 4; ++i)
#pragma unroll
        for (int j = 0; j < 4; ++j) {
            f32x4 z4 = {0.f, 0.f, 0.f, 0.f};
            acc[i][j] = z4;
        }

    // B stage: 4 async gload_lds per thread; linear LDS dest, inverse-swizzled src
    auto stageB = [&](int kt, int buf) {
        const int k0 = kt * BK;
#pragma unroll
        for (int c = 0; c < 4; ++c) {
            const int pbase = (c * 4 + wav) * 64;   // wave-uniform chunk base
            const int p  = pbase + lane;            // phys chunk this lane fills
            const int o  = p >> 2;
            const int sp = p & 3;
            const int sl = sp ^ ((o >> 1) & 3);     // logical chunk that belongs here
            gload_lds16(wg + (size_t)o * NK + k0 + sl * 8,
                        (void*)((__bf16*)&Bs[buf][0][0] + (size_t)pbase * 8));
        }
    };

    // prologue
    {
        const float* p = xg + (size_t)ar * NK + 0 * BK + asl * 8;
        f32x4 a0 = *(const f32x4*)p;
        f32x4 a1 = *(const f32x4*)(p + 4);
        stageB(0, 0);
        bf16x8 av;
#pragma unroll
        for (int e = 0; e < 4; ++e) { av[e] = (__bf16)a0[e]; av[e + 4] = (__bf16)a1[e]; }
        *(bf16x8*)&As[0][ar][asp * 8] = av;
    }
    __syncthreads();

#pragma unroll
    for (int kt = 0; kt < NKT; ++kt) {
        const int cur = kt & 1;
        if (kt + 1 < NKT) {
            // issue A global loads FIRST so their vmcnt wait doesn't drain the
            // (younger) async gload_lds queue; then B async; then cvt+ds_write A
            const float* p = xg + (size_t)ar * NK + (kt + 1) * BK + asl * 8;
            f32x4 a0 = *(const f32x4*)p;
            f32x4 a1 = *(const f32x4*)(p + 4);
            stageB(kt + 1, cur ^ 1);
            bf16x8 av;
#pragma unroll
            for (int e = 0; e < 4; ++e) { av[e] = (__bf16)a0[e]; av[e + 4] = (__bf16)a1[e]; }
            *(bf16x8*)&As[cur ^ 1][ar][asp * 8] = av;
        }

        bf16x8 afr[4];
#pragma unroll
        for (int i = 0; i < 4; ++i)
            afr[i] = *(const bf16x8*)&As[cur][i * 16 + lr][sfrag];
#pragma unroll
        for (int j = 0; j < 4; ++j) {
            bf16x8 bfr = *(const bf16x8*)&Bs[cur][wav * 64 + j * 16 + lr][sfrag];
#pragma unroll
            for (int i = 0; i < 4; ++i)
                // A-operand := Wt frag, B-operand := x frag -> D[o][batch];
                // lane holds 4 consecutive o at one batch row -> f32x4 stores
                acc[i][j] = mfma16(bfr, afr[i], acc[i][j]);
        }
        __syncthreads();
    }

    // epilogue: C/D 16x16x32 layout: batch = i*16 + (lane&15), o = j*16 + lg*4 + r
#pragma unroll
    for (int i = 0; i < 4; ++i) {
        const size_t rowbase = (size_t)(i * 16 + lr) * NO;
#pragma unroll
        for (int j = 0; j < 4; ++j) {
            f32x4 res;
#pragma unroll
            for (int r = 0; r < 4; ++r)
                res[r] = softplus_f(acc[i][j][r] + bb[j][r]);
            *(f32x4*)(og + rowbase + wav * 64 + j * 16 + lg * 4) = res;
        }
    }
}

extern "C" void kernel_launch(void* const* d_in, const int* in_sizes, int n_in,
                              void* d_out, int out_size, void* d_ws, size_t ws_size,
                              hipStream_t stream) {
    const float* x  = (const float*)d_in[0];
    const float* w  = (const float*)d_in[1];
    const float* b  = (const float*)d_in[2];
    float* out      = (float*)d_out;
    __bf16* wt      = (__bf16*)d_ws;   // 32*256*256*2 B = 4 MB scratch

    // 1) transpose+convert W -> Wt bf16 (runs every call; deterministic)
    hipLaunchKernelGGL(prep_wt_kernel, dim3(1024), dim3(256), 0, stream, w, wt);
    // 2) grouped GEMM + bias + softplus
    hipLaunchKernelGGL(mv_dense_kernel, dim3(NV * (NB / BM)), dim3(256), 0, stream,
                       x, wt, b, out);
}

// Round 3
// 86.177 us; speedup vs baseline: 1.4563x; 1.0467x over previous
//
#include <hip/hip_runtime.h>
#include <stdint.h>
#include <math.h>

// Problem constants
#define NV 32      // num_vari (groups)
#define NB 4096    // batch
#define NK 256     // 2*dim_per_vari (contraction)
#define NO 256     // dim_to (output features)
#define BM 64      // batch rows per block

typedef __bf16 bf16x8 __attribute__((ext_vector_type(8)));
typedef __bf16 bf16x4 __attribute__((ext_vector_type(4)));
typedef float  f32x4  __attribute__((ext_vector_type(4)));

__device__ __forceinline__ f32x4 mfma16(bf16x8 a, bf16x8 b, f32x4 c) {
    return __builtin_amdgcn_mfma_f32_16x16x32_bf16(a, b, c, 0, 0, 0);
}

__device__ __forceinline__ float softplus_f(float z) {
    // stable: max(z,0) + log(1+exp(-|z|)); fast-math err ~1e-3 << 1.055 threshold
    return fmaxf(z, 0.0f) + __logf(1.0f + __expf(-fabsf(z)));
}

// ---------------------------------------------------------------------------
// prep: W[v][k][o] fp32  ->  Wt[v][o][k] bf16  (transpose + convert, 4 MB)
__global__ __launch_bounds__(256)
void prep_wt_kernel(const float* __restrict__ w, __bf16* __restrict__ wt) {
    const int id = blockIdx.x * 256 + threadIdx.x;   // 32*256*32 = 262144
    const int o  = id & 255;
    const int kc = (id >> 8) & 31;    // 8-k chunk
    const int v  = id >> 13;
    const float* src = w + ((size_t)v * NK + (size_t)kc * 8) * NO + o;
    bf16x8 r;
#pragma unroll
    for (int j = 0; j < 8; ++j) r[j] = (__bf16)src[(size_t)j * NO];
    *(bf16x8*)(wt + ((size_t)v * NO + o) * NK + kc * 8) = r;
}

// ---------------------------------------------------------------------------
// main: out[v][b][o] = softplus( x[v][b][:] . Wt[v][o][:] + 256*bias[v][o] )
// Structure: ONE vmcnt drain per block. x-tile staged to LDS once (bf16,
// XOR-swizzled); W streamed per K-step straight from L2 into registers
// (distance-1 prefetch); K-loop has NO barriers.
__global__ __launch_bounds__(512, 4)
void mv_dense_kernel(const float* __restrict__ x, const __bf16* __restrict__ wt,
                     const float* __restrict__ bias, float* __restrict__ out) {
    // As[row][k], 64 rows x 256 k bf16 = 32 KB. 16B-chunk swizzle:
    //   phys(c, r) = c ^ (r & 7) ^ (((c >> 3) & 3) << 1)
    // -> full-row ds_writes bijective (uniform banks) and the stride-512B
    //    fragment ds_reads land 8 bank-slots x 8 lanes (minimal rounds).
    __shared__ __bf16 As[BM * NK];

    const int t    = threadIdx.x;
    const int w    = t >> 6;      // wave 0..7 -> o-columns [w*32, w*32+32)
    const int lane = t & 63;
    const int lr   = lane & 15;
    const int lg   = lane >> 4;

    // XCD-chunked swizzle: 2048 = 8 XCD x 256; same-v blocks share one L2
    const int bid = blockIdx.x;
    const int bsw = (bid & 7) * 256 + (bid >> 3);
    const int v   = bsw >> 6;
    const int mb  = bsw & 63;

    const float*  xg = x    + ((size_t)v * NB + (size_t)mb * BM) * NK;
    const __bf16* wg = wt   + (size_t)v * NO * NK;
    const float*  bg = bias + (size_t)v * NO;
    float*        og = out  + ((size_t)v * NB + (size_t)mb * BM) * NO;

    // ---- issue the x HBM loads first (the long-latency stream) ----
    // lane-contiguous: wave covers 1 KB contiguous per instruction
    f32x4 xa[8];
#pragma unroll
    for (int m = 0; m < 8; ++m)
        xa[m] = *(const f32x4*)(xg + m * 2048 + t * 4);

    // W fragment pointers for this wave (o rows; k advances by kk*32)
    const __bf16* wb0 = wg + (size_t)(w * 32 + lr) * NK + lg * 8;       // j=0
    const __bf16* wb1 = wb0 + (size_t)16 * NK;                          // j=1

    // prefetch W for kk=0 (L2)
    bf16x8 bcur0 = *(const bf16x8*)wb0;
    bf16x8 bcur1 = *(const bf16x8*)wb1;

    // bias, pre-scaled by 256, laid out per C-fragment
    f32x4 bb[2];
#pragma unroll
    for (int j = 0; j < 2; ++j) {
        f32x4 bv = *(const f32x4*)(bg + w * 32 + j * 16 + lg * 4);
#pragma unroll
        for (int r = 0; r < 4; ++r) bb[j][r] = 256.0f * bv[r];
    }

    // ---- cvt + stage x: wave w writes full row (m*8+w) per instruction ----
    {
        const int c    = lane >> 1;   // 16B chunk index in row (k = lane*4)
        const int half = lane & 1;
#pragma unroll
        for (int m = 0; m < 8; ++m) {
            const int r    = m * 8 + w;
            const int phys = c ^ (r & 7) ^ (((c >> 3) & 3) << 1);
            bf16x4 bv;
#pragma unroll
            for (int e = 0; e < 4; ++e) bv[e] = (__bf16)xa[m][e];
            *(bf16x4*)&As[r * NK + phys * 8 + half * 4] = bv;
        }
    }
    __syncthreads();   // the ONLY barrier

    f32x4 acc[4][2];
#pragma unroll
    for (int i = 0; i < 4; ++i)
#pragma unroll
        for (int j = 0; j < 2; ++j) {
            f32x4 z4 = {0.f, 0.f, 0.f, 0.f};
            acc[i][j] = z4;
        }

    // ---- K loop: ds_read A frags + L2-stream W frags + MFMA; no barriers ----
#pragma unroll
    for (int kk = 0; kk < 8; ++kk) {
        bf16x8 bnxt0, bnxt1;
        if (kk < 7) {   // distance-1 register prefetch from L2
            bnxt0 = *(const bf16x8*)(wb0 + (kk + 1) * 32);
            bnxt1 = *(const bf16x8*)(wb1 + (kk + 1) * 32);
        }
        // A fragments: row = i*16+lr, k-chunk c = kk*4+lg (8 contiguous k)
        bf16x8 afr[4];
        const int cbase = kk * 4 + lg;
        const int cx    = ((kk >> 1) & 3) << 1;   // ((c>>3)&3)<<1, lane-invariant
#pragma unroll
        for (int i = 0; i < 4; ++i) {
            const int row  = i * 16 + lr;
            const int phys = cbase ^ (row & 7) ^ cx;
            afr[i] = *(const bf16x8*)&As[row * NK + phys * 8];
        }
#pragma unroll
        for (int i = 0; i < 4; ++i) {
            // A-operand := Wt frag, B-operand := x frag -> D[o][batch]
            acc[i][0] = mfma16(bcur0, afr[i], acc[i][0]);
            acc[i][1] = mfma16(bcur1, afr[i], acc[i][1]);
        }
        bcur0 = bnxt0;
        bcur1 = bnxt1;
    }

    // ---- epilogue: batch = i*16 + lr, o = w*32 + j*16 + lg*4 + r ----
#pragma unroll
    for (int i = 0; i < 4; ++i) {
        const size_t rowbase = (size_t)(i * 16 + lr) * NO;
#pragma unroll
        for (int j = 0; j < 2; ++j) {
            f32x4 res;
#pragma unroll
            for (int r = 0; r < 4; ++r)
                res[r] = softplus_f(acc[i][j][r] + bb[j][r]);
            *(f32x4*)(og + rowbase + w * 32 + j * 16 + lg * 4) = res;
        }
    }
}

extern "C" void kernel_launch(void* const* d_in, const int* in_sizes, int n_in,
                              void* d_out, int out_size, void* d_ws, size_t ws_size,
                              hipStream_t stream) {
    const float* x  = (const float*)d_in[0];
    const float* w  = (const float*)d_in[1];
    const float* b  = (const float*)d_in[2];
    float* out      = (float*)d_out;
    __bf16* wt      = (__bf16*)d_ws;   // 32*256*256*2 B = 4 MB scratch

    // 1) transpose+convert W -> Wt bf16
    hipLaunchKernelGGL(prep_wt_kernel, dim3(1024), dim3(256), 0, stream, w, wt);
    // 2) grouped GEMM + bias + softplus (one drain per block, barrier-free K loop)
    hipLaunchKernelGGL(mv_dense_kernel, dim3(NV * (NB / BM)), dim3(512), 0, stream,
                       x, wt, b, out);
}